// Round 2
// baseline (5455.891 us; speedup 1.0000x reference)
//
#include <hip/hip_runtime.h>

#define DEV __device__ __forceinline__

typedef __attribute__((ext_vector_type(8))) short short8;
typedef __attribute__((ext_vector_type(4))) float floatx4;
typedef unsigned long long ull;

static constexpr int B_ = 512, T_ = 912, H_ = 128, F_ = 32;
static constexpr size_t HN_OFF   = 1024;                       // bf16 hN[4][512][128]
static constexpr size_t XT_OFF   = HN_OFF + (size_t)4 * 512 * 128 * 2;   // 525312
static constexpr size_t RING_OFF = XT_OFF + (size_t)T_ * B_ * F_ * 2;    // 30409728
// ring per boundary-group: 8 chunks x 64KB (chunk = [8 slots][32 rows][256B])
static constexpr size_t RING_BPG = 8 * 65536;                  // 512 KB

template <int N> struct IC { static constexpr int value = N; };

DEV unsigned short bf16rne(float f) {
    unsigned u = __builtin_bit_cast(unsigned, f);
    u += 0x7FFFu + ((u >> 16) & 1u);
    return (unsigned short)(u >> 16);
}
DEV float bf16tof(unsigned short u) {
    return __builtin_bit_cast(float, ((unsigned)u) << 16);
}
DEV float fastsig(float y) {     // rcp(1+exp2(y))
    return __builtin_amdgcn_rcpf(1.f + __builtin_amdgcn_exp2f(y));
}
DEV float sigm(float x) { return fastsig(-1.44269504f * x); }
DEV unsigned ald(const unsigned* p) {
    return __hip_atomic_load(p, __ATOMIC_RELAXED, __HIP_MEMORY_SCOPE_AGENT);
}
DEV void ast32(unsigned* p, unsigned v) {
    __hip_atomic_store(p, v, __ATOMIC_RELAXED, __HIP_MEMORY_SCOPE_AGENT);
}
DEV ull ald8(const ull* p) {
    return __hip_atomic_load(p, __ATOMIC_RELAXED, __HIP_MEMORY_SCOPE_AGENT);
}
DEV void ast8(ull* p, ull v) {
    __hip_atomic_store(p, v, __ATOMIC_RELAXED, __HIP_MEMORY_SCOPE_AGENT);
}
DEV void bar_fast() {            // LDS-only barrier: no vmcnt drain
    asm volatile("s_waitcnt lgkmcnt(0)\n\ts_barrier" ::: "memory");
}

// ---------------------------------------------------------------------------
// x [B][T][32] fp32  ->  xT [T][B][32] bf16
__global__ __launch_bounds__(256) void xpose(const float* __restrict__ x,
                                             unsigned short* __restrict__ xT) {
    int tid = blockIdx.x * 256 + threadIdx.x;
    if (tid >= B_ * T_ * 4) return;
    int k = tid & 3;
    int r = tid >> 2;                                  // r = b*912 + t
    int b = r / T_;
    int t = r - b * T_;
    const float* p = x + ((size_t)r * 32 + k * 8);
    short8 v;
#pragma unroll
    for (int j = 0; j < 8; j++) v[j] = (short)bf16rne(p[j]);
    *(short8*)(xT + ((size_t)t * 512 + b) * 32 + k * 8) = v;
}

// ---------------------------------------------------------------------------
// Pipelined 4-layer LSTM scan. 64 blocks = 4 layers x 16 groups (32 samples).
// 8-slot h-ring (Ah) + 8-slot x-stage (Xl) in LDS; per-step DISTRIBUTED
// export (h(t-1) -> ring, full-sector tid*8 stores) and x prefetch/stage
// (ring -> regs -> LDS, tid-partitioned so each byte is loaded once per
// block and broadcast via LDS). Intra-step LDS slots are disjoint:
// write u (h), u+6 (stage); read u+1 (x frags), u+7 (h frags + export src).
__global__ __launch_bounds__(512, 2) void lstm_scan(
    const float* __restrict__ Wih0, const float* __restrict__ Whh0,
    const float* __restrict__ bih0, const float* __restrict__ bhh0,
    const float* __restrict__ Wih123, const float* __restrict__ Whh123,
    const float* __restrict__ bih123, const float* __restrict__ bhh123,
    char* __restrict__ ws) {
    const int tid  = threadIdx.x;
    const int wv   = tid >> 6;
    const int lane = tid & 63;
    const int col  = lane & 15;
    const int quad = lane >> 4;
    const int layer = blockIdx.x >> 4;
    const int grp   = blockIdx.x & 15;
    const int b0    = grp * 32;
    const bool lay0 = (layer == 0);

    unsigned* flags = (unsigned*)ws;                   // [4][16] chunks published
    unsigned* cons  = (unsigned*)(ws + 512);           // [4][16] consumer progress
    char* hN8 = ws + HN_OFF;
    const char* xTB = ws + XT_OFF;

    __shared__ unsigned short Ah[8][32][132];          // h history ring (slot = t&7)
    __shared__ unsigned short Xl[8][32][132];          // staged input (slot = t&7)
    char* AhB = (char*)Ah;
    char* XlB = (char*)Xl;

    for (int i = tid; i < 8 * 32 * 132; i += 512) {
        ((unsigned short*)Ah)[i] = 0;
        ((unsigned short*)Xl)[i] = 0;
    }

    // ---- persistent weights, activation scale folded in ------------------
    short8 wh[4][4];
    short8 wx[4][4];
    float  bias_q[4];
    {
        const float *Wih, *Whh, *bih, *bhh;
        int kin, KX;
        if (layer == 0) { Wih = Wih0; Whh = Whh0; bih = bih0; bhh = bhh0; kin = 32; KX = 1; }
        else {
            Wih = Wih123 + (size_t)(layer - 1) * 512 * 128;
            Whh = Whh123 + (size_t)(layer - 1) * 512 * 128;
            bih = bih123 + (size_t)(layer - 1) * 512;
            bhh = bhh123 + (size_t)(layer - 1) * 512;
            kin = 128; KX = 4;
        }
#pragma unroll
        for (int q = 0; q < 4; q++) {
            const float sc = (q == 2) ? -2.88539008f : -1.44269504f;
            int row = q * 128 + wv * 16 + col;
            bias_q[q] = (bih[row] + bhh[row]) * sc;
#pragma unroll
            for (int kt = 0; kt < 4; kt++) {
                const float* ph = Whh + (size_t)row * 128 + kt * 32 + quad * 8;
                short8 v;
#pragma unroll
                for (int j = 0; j < 8; j++) v[j] = (short)bf16rne(ph[j] * sc);
                wh[q][kt] = v;
            }
#pragma unroll
            for (int kt = 0; kt < 4; kt++) {
                short8 v = {0, 0, 0, 0, 0, 0, 0, 0};
                if (kt < KX) {
                    const float* px = Wih + (size_t)row * kin + kt * 32 + quad * 8;
#pragma unroll
                    for (int j = 0; j < 8; j++) v[j] = (short)bf16rne(px[j] * sc);
                }
                wx[q][kt] = v;
            }
        }
    }

    unsigned* myflag   = &flags[layer * 16 + grp];
    unsigned* prevflag = &flags[(layer > 0 ? layer - 1 : 0) * 16 + grp];
    unsigned* mycons   = &cons[(layer > 0 ? layer - 1 : 0) * 16 + grp];
    unsigned* nextcons = &cons[layer * 16 + grp];
    char* prodRing = ws + RING_OFF + (size_t)(layer * 16 + grp) * RING_BPG;
    char* consRing = ws + RING_OFF + (size_t)((layer > 0 ? layer - 1 : 0) * 16 + grp) * RING_BPG;

    // precomputed byte offsets (constants through the whole kernel)
    const int ahrd  = col * 264 + quad * 16;                    // A-frag base
    const int hwr   = (quad * 4) * 264 + (wv * 16 + col) * 2;   // h write base
    const int exA   = (tid >> 5) * 264 + (tid & 31) * 8;        // export/stage LDS base
    const int rgo   = tid << 3;                                 // ring byte offset (tid*8)
    const int xoff0 = (b0 + col) * 64 + quad * 16;              // xT A-frag lane off

    const short8 z8 = {0, 0, 0, 0, 0, 0, 0, 0};
    ull xr0[2] = {0, 0}, xr1[2] = {0, 0};              // x prefetch ping-pong
    unsigned pf = 0, pc = 0;
    float c8[8] = {0.f, 0.f, 0.f, 0.f, 0.f, 0.f, 0.f, 0.f};
    floatx4 accx[4][2];                                // carried x-part partials

    __syncthreads();                                   // LDS zeros visible

    // ---- prologue --------------------------------------------------------
    if (!lay0) {
        if (tid == 0) { while (ald(prevflag) < 2u) {} }
        __syncthreads();
#pragma unroll
        for (int s = 0; s < 6; s++) {                  // stage x(0..5)
            ull a = ald8((const ull*)(consRing + s * 8192 + rgo));
            ull b = ald8((const ull*)(consRing + s * 8192 + rgo + 4096));
            *(ull*)(XlB + s * 8448 + exA) = a;
            *(ull*)(XlB + s * 8448 + exA + 4224) = b;
        }
        xr0[0] = ald8((const ull*)(consRing + 6 * 8192 + rgo));          // x(6)
        xr1[0] = ald8((const ull*)(consRing + 6 * 8192 + rgo + 4096));
        __syncthreads();
    }
    {   // accx for t=0
        short8 ax0[4], ax1[4];
        if (!lay0) {
#pragma unroll
            for (int kt = 0; kt < 4; kt++) {
                ax0[kt] = *(const short8*)(XlB + ahrd + kt * 64);
                ax1[kt] = *(const short8*)(XlB + ahrd + 4224 + kt * 64);
            }
        } else {
            const char* px = xTB + xoff0;              // t = 0
            ax0[0] = *(const short8*)px;
            ax1[0] = *(const short8*)(px + 1024);
#pragma unroll
            for (int kt = 1; kt < 4; kt++) { ax0[kt] = z8; ax1[kt] = z8; }
        }
#pragma unroll
        for (int q = 0; q < 4; q++) {
            floatx4 a = {bias_q[q], bias_q[q], bias_q[q], bias_q[q]};
            accx[q][0] = a; accx[q][1] = a;
        }
#pragma unroll
        for (int kt = 0; kt < 4; kt++)
#pragma unroll
            for (int q = 0; q < 4; q++) {
                accx[q][0] = __builtin_amdgcn_mfma_f32_16x16x32_bf16(ax0[kt], wx[q][kt], accx[q][0], 0, 0, 0);
                accx[q][1] = __builtin_amdgcn_mfma_f32_16x16x32_bf16(ax1[kt], wx[q][kt], accx[q][1], 0, 0, 0);
            }
    }

    int c = 0;
    auto step = [&](auto UC) {
        constexpr int u   = UC.value;
        constexpr bool bnd = (u == 0 || u == 8);
        constexpr bool stg = (u == 3 || u == 11);
        constexpr bool ver = (u == 7 || u == 15);
        constexpr int pp  = u & 1;
        const int cc = c + (u >> 3);
        const int t  = c * 8 + u;

        if (bnd && tid == 0) {
            if (layer > 0 && cc <= 111) pf = ald(prevflag);
            if (layer < 3 && cc >= 7)   pc = ald(nextcons);
        }

        // ---- export h(t-1) -> ring (full-sector tid*8 stores) -------------
        if (layer < 3) {
            constexpr int eCh = (u == 0) ? -1 : ((u - 1) >> 3);
            constexpr int eSl = (u + 7) & 7;
            const char* es = AhB + eSl * 8448 + exA;
            ull h0 = *(const ull*)es;
            ull h1 = *(const ull*)(es + 4224);
            char* rb = prodRing + (size_t)((c + eCh) & 7) * 65536 + eSl * 8192 + rgo;
            ast8((ull*)rb, h0);
            ast8((ull*)(rb + 4096), h1);
        }

        // ---- ring prefetch x(t+7) (non-stg steps: issue early) ------------
        if (!lay0) {
            if constexpr (!stg) {
                constexpr int rk  = (u + 7) >> 3;
                constexpr int rSl = (u + 7) & 7;
                const char* rp = consRing + (size_t)((c + rk) & 7) * 65536 + rSl * 8192 + rgo;
                xr0[pp ^ 1] = ald8((const ull*)rp);
                xr1[pp ^ 1] = ald8((const ull*)(rp + 4096));
            }
            // ---- stage x(t+6) into Xl slot (u+6)&7 ------------------------
            constexpr int sSl = (u + 6) & 7;
            char* sd = XlB + sSl * 8448 + exA;
            *(ull*)sd = xr0[pp];
            *(ull*)(sd + 4224) = xr1[pp];
        }

        // ---- layer0: x(t+1) A-frags direct from xT ------------------------
        short8 a0x, a1x;
        if (lay0) {
            const int tt = (t < 911) ? t + 1 : 911;
            const char* px = xTB + (size_t)tt * 32768 + xoff0;
            a0x = *(const short8*)px;
            a1x = *(const short8*)(px + 1024);
        }

        // ---- A fragments: h(t-1) from slot (u+7)&7 ------------------------
        constexpr int hSl = (u + 7) & 7;
        short8 ah0[4], ah1[4];
        const char* ab = AhB + hSl * 8448 + ahrd;
#pragma unroll
        for (int kt = 0; kt < 4; kt++) {
            ah0[kt] = *(const short8*)(ab + kt * 64);
            ah1[kt] = *(const short8*)(ab + 4224 + kt * 64);
        }
        // ---- x(t+1) A-frags from Xl slot (u+1)&7 --------------------------
        short8 ax0[4], ax1[4];
        if (!lay0) {
            constexpr int xSl = (u + 1) & 7;
            const char* xab = XlB + xSl * 8448 + ahrd;
#pragma unroll
            for (int kt = 0; kt < 4; kt++) {
                ax0[kt] = *(const short8*)(xab + kt * 64);
                ax1[kt] = *(const short8*)(xab + 4224 + kt * 64);
            }
        } else {
            ax0[0] = a0x; ax1[0] = a1x;
#pragma unroll
            for (int kt = 1; kt < 4; kt++) { ax0[kt] = z8; ax1[kt] = z8; }
        }

        // ---- recurrent part: acc = accx + h(t-1)*Wh -----------------------
        floatx4 acc[4][2];
#pragma unroll
        for (int q = 0; q < 4; q++) { acc[q][0] = accx[q][0]; acc[q][1] = accx[q][1]; }
#pragma unroll
        for (int kt = 0; kt < 4; kt++)
#pragma unroll
            for (int q = 0; q < 4; q++) {
                acc[q][0] = __builtin_amdgcn_mfma_f32_16x16x32_bf16(ah0[kt], wh[q][kt], acc[q][0], 0, 0, 0);
                acc[q][1] = __builtin_amdgcn_mfma_f32_16x16x32_bf16(ah1[kt], wh[q][kt], acc[q][1], 0, 0, 0);
            }

        // ---- gates(t) INTERLEAVED with x-MFMAs for t+1 --------------------
#pragma unroll
        for (int q = 0; q < 4; q++) {
            floatx4 a = {bias_q[q], bias_q[q], bias_q[q], bias_q[q]};
            accx[q][0] = a; accx[q][1] = a;
        }
        char* hb = AhB + (u & 7) * 8448 + hwr;
#pragma unroll
        for (int rt = 0; rt < 2; rt++)
#pragma unroll
            for (int r = 0; r < 4; r++) {
                float iv = fastsig(acc[0][rt][r]);
                float fv = fastsig(acc[1][rt][r]);
                float gr = fastsig(acc[2][rt][r]);     // (tanh(g)+1)/2
                float ov = fastsig(acc[3][rt][r]);
#pragma unroll
                for (int q = 0; q < 4; q++)
                    accx[q][rt] = __builtin_amdgcn_mfma_f32_16x16x32_bf16(
                        rt ? ax1[r] : ax0[r], wx[q][r], accx[q][rt], 0, 0, 0);
                float gt = 2.f * gr - 1.f;
                const int ci = rt * 4 + r;
                float cv = fv * c8[ci] + iv * gt;
                c8[ci] = cv;
                float rc = fastsig(-2.88539008f * cv);
                float hv = ov * (2.f * rc - 1.f);
                *(unsigned short*)(hb + rt * 4224 + r * 264) = bf16rne(hv);
            }

        // ---- sync cadence -------------------------------------------------
        if constexpr (stg) {
            __syncthreads();                           // full drain: release point
            if (tid == 0) {
                if (layer < 3 && cc >= 1) ast32(myflag, (unsigned)cc);
                if (layer > 0) ast32(mycons, (unsigned)cc);
            }
            if (!lay0) {                               // late issue of x(t+7)
                constexpr int rk  = (u + 7) >> 3;
                constexpr int rSl = (u + 7) & 7;
                const char* rp = consRing + (size_t)((c + rk) & 7) * 65536 + rSl * 8192 + rgo;
                xr0[pp ^ 1] = ald8((const ull*)rp);
                xr1[pp ^ 1] = ald8((const ull*)(rp + 4096));
            }
        } else {
            if (ver && tid == 0) {
                if (layer > 0 && cc <= 111) {
                    unsigned tgt = cc + 3;
                    if (pf < tgt) while (ald(prevflag) < tgt) {}
                }
                if (layer < 3 && cc >= 7) {
                    unsigned tgt = cc - 6;
                    if (pc < tgt) while (ald(nextcons) < tgt) {}
                }
            }
            bar_fast();
        }
    };

    for (c = 0; c < 114; c += 2) {
        step(IC<0>{});  step(IC<1>{});  step(IC<2>{});  step(IC<3>{});
        step(IC<4>{});  step(IC<5>{});  step(IC<6>{});  step(IC<7>{});
        step(IC<8>{});  step(IC<9>{});  step(IC<10>{}); step(IC<11>{});
        step(IC<12>{}); step(IC<13>{}); step(IC<14>{}); step(IC<15>{});
    }

    // ---- epilogue: export h(911) (slot 7), publish, export hN ------------
    if (layer < 3) {
        const char* es = AhB + 7 * 8448 + exA;
        ull h0 = *(const ull*)es;
        ull h1 = *(const ull*)(es + 4224);
        char* rb = prodRing + (size_t)(113 & 7) * 65536 + 7 * 8192 + rgo;
        ast8((ull*)rb, h0);
        ast8((ull*)(rb + 4096), h1);
    }
    __syncthreads();                                   // drain ring stores
    if (tid == 0 && layer < 3) ast32(myflag, 114u);
    {
        const char* es = AhB + 7 * 8448 + exA;         // h[911]
        ull h0 = *(const ull*)es;
        ull h1 = *(const ull*)(es + 4224);
        char* dst = hN8 + ((size_t)layer * 512 + b0 + (tid >> 5)) * 256 + (tid & 31) * 8;
        *(ull*)dst = h0;
        *(ull*)(dst + 16 * 256) = h1;
    }
}

// ---------------------------------------------------------------------------
// heads: hN [4][512][128] bf16 -> opt/tp/sl/lot, each [4][512][4] fp32
__global__ __launch_bounds__(256) void heads(
    const unsigned short* __restrict__ hN,
    const float* __restrict__ Wopt, const float* __restrict__ bopt,
    const float* __restrict__ Wlot, const float* __restrict__ blot,
    const float* __restrict__ Wtp,  const float* __restrict__ btp,
    const float* __restrict__ Wsl,  const float* __restrict__ bsl,
    float* __restrict__ out) {
    int tid = blockIdx.x * 256 + threadIdx.x;
    if (tid >= 4 * 4 * 512) return;
    int b  = tid & 511;
    int l  = (tid >> 9) & 3;
    int hd = tid >> 11;
    const float *W, *bb;
    if      (hd == 0) { W = Wopt; bb = bopt; }
    else if (hd == 1) { W = Wtp;  bb = btp;  }
    else if (hd == 2) { W = Wsl;  bb = bsl;  }
    else              { W = Wlot; bb = blot; }
    const unsigned short* h = hN + ((size_t)l * 512 + b) * 128;
    float z0 = bb[0], z1 = bb[1], z2 = bb[2], z3 = bb[3];
    for (int i = 0; i < 128; i++) {
        float hv = bf16tof(h[i]);
        z0 += hv * W[0 * 128 + i];
        z1 += hv * W[1 * 128 + i];
        z2 += hv * W[2 * 128 + i];
        z3 += hv * W[3 * 128 + i];
    }
    float o0, o1, o2, o3;
    if (hd == 0) {
        float m = fmaxf(fmaxf(z0, z1), fmaxf(z2, z3));
        float e0 = __builtin_amdgcn_exp2f((z0 - m) * 1.44269504f);
        float e1 = __builtin_amdgcn_exp2f((z1 - m) * 1.44269504f);
        float e2 = __builtin_amdgcn_exp2f((z2 - m) * 1.44269504f);
        float e3 = __builtin_amdgcn_exp2f((z3 - m) * 1.44269504f);
        float rs = __builtin_amdgcn_rcpf(e0 + e1 + e2 + e3);
        float p0 = e0 * rs, p1 = e1 * rs, p2 = e2 * rs, p3 = e3 * rs;
        float m2 = fmaxf(fmaxf(p0, p1), fmaxf(p2, p3));
        float f0 = __builtin_amdgcn_exp2f((p0 - m2) * 1.44269504f);
        float f1 = __builtin_amdgcn_exp2f((p1 - m2) * 1.44269504f);
        float f2 = __builtin_amdgcn_exp2f((p2 - m2) * 1.44269504f);
        float f3 = __builtin_amdgcn_exp2f((p3 - m2) * 1.44269504f);
        float rs2 = __builtin_amdgcn_rcpf(f0 + f1 + f2 + f3);
        o0 = f0 * rs2; o1 = f1 * rs2; o2 = f2 * rs2; o3 = f3 * rs2;
    } else {
        o0 = sigm(sigm(z0)); o1 = sigm(sigm(z1));
        o2 = sigm(sigm(z2)); o3 = sigm(sigm(z3));
    }
    float* o = out + (size_t)hd * 8192 + ((size_t)l * 512 + b) * 4;
    o[0] = o0; o[1] = o1; o[2] = o2; o[3] = o3;
}

// ---------------------------------------------------------------------------
extern "C" void kernel_launch(void* const* d_in, const int* in_sizes, int n_in,
                              void* d_out, int out_size, void* d_ws, size_t ws_size,
                              hipStream_t stream) {
    (void)in_sizes; (void)n_in; (void)out_size; (void)ws_size;
    const float* x      = (const float*)d_in[0];
    const float* Wih0   = (const float*)d_in[1];
    const float* Whh0   = (const float*)d_in[2];
    const float* bih0   = (const float*)d_in[3];
    const float* bhh0   = (const float*)d_in[4];
    const float* Wih123 = (const float*)d_in[5];
    const float* Whh123 = (const float*)d_in[6];
    const float* bih123 = (const float*)d_in[7];
    const float* bhh123 = (const float*)d_in[8];
    const float* Wopt = (const float*)d_in[9];
    const float* bopt = (const float*)d_in[10];
    const float* Wlot = (const float*)d_in[11];
    const float* blot = (const float*)d_in[12];
    const float* Wtp  = (const float*)d_in[13];
    const float* btp  = (const float*)d_in[14];
    const float* Wsl  = (const float*)d_in[15];
    const float* bsl  = (const float*)d_in[16];
    char* ws = (char*)d_ws;

    hipMemsetAsync(ws, 0, 1024, stream);               // flags + cons
    xpose<<<(B_ * T_ * 4 + 255) / 256, 256, 0, stream>>>(x, (unsigned short*)(ws + XT_OFF));
    lstm_scan<<<64, 512, 0, stream>>>(Wih0, Whh0, bih0, bhh0,
                                      Wih123, Whh123, bih123, bhh123, ws);
    heads<<<32, 256, 0, stream>>>((const unsigned short*)(ws + HN_OFF),
                                  Wopt, bopt, Wlot, blot, Wtp, btp, Wsl, bsl,
                                  (float*)d_out);
}

// Round 3
// 4555.636 us; speedup vs baseline: 1.1976x; 1.1976x over previous
//
#include <hip/hip_runtime.h>

#define DEV __device__ __forceinline__

typedef __attribute__((ext_vector_type(8))) short short8;
typedef __attribute__((ext_vector_type(4))) float floatx4;
typedef unsigned long long ull;

static constexpr int B_ = 512, T_ = 912, H_ = 128, F_ = 32;
static constexpr size_t HN_OFF   = 1024;                       // bf16 hN[4][512][128]
static constexpr size_t XT_OFF   = HN_OFF + (size_t)4 * 512 * 128 * 2;   // 525312
static constexpr size_t RING_OFF = XT_OFF + (size_t)T_ * B_ * F_ * 2;    // 30409728
// ring per (layer,group16): 8 chunks x 32KB (chunk = [8 slots][16 rows][256B])
static constexpr size_t RING_BPG = 8 * 32768;                  // 256 KB

template <int N> struct IC { static constexpr int value = N; };

DEV unsigned short bf16rne(float f) {
    unsigned u = __builtin_bit_cast(unsigned, f);
    u += 0x7FFFu + ((u >> 16) & 1u);
    return (unsigned short)(u >> 16);
}
DEV float bf16tof(unsigned short u) {
    return __builtin_bit_cast(float, ((unsigned)u) << 16);
}
DEV float fastsig(float y) {     // rcp(1+exp2(y))
    return __builtin_amdgcn_rcpf(1.f + __builtin_amdgcn_exp2f(y));
}
DEV float sigm(float x) { return fastsig(-1.44269504f * x); }
DEV unsigned ald(const unsigned* p) {
    return __hip_atomic_load(p, __ATOMIC_RELAXED, __HIP_MEMORY_SCOPE_AGENT);
}
DEV void ast32(unsigned* p, unsigned v) {
    __hip_atomic_store(p, v, __ATOMIC_RELAXED, __HIP_MEMORY_SCOPE_AGENT);
}
DEV ull ald8(const ull* p) {
    return __hip_atomic_load(p, __ATOMIC_RELAXED, __HIP_MEMORY_SCOPE_AGENT);
}
DEV void ast8(ull* p, ull v) {
    __hip_atomic_store(p, v, __ATOMIC_RELAXED, __HIP_MEMORY_SCOPE_AGENT);
}
DEV void bar_fast() {            // LDS-only barrier: no vmcnt drain
    asm volatile("s_waitcnt lgkmcnt(0)\n\ts_barrier" ::: "memory");
}

// ---------------------------------------------------------------------------
// x [B][T][32] fp32  ->  xT [T][B][32] bf16
__global__ __launch_bounds__(256) void xpose(const float* __restrict__ x,
                                             unsigned short* __restrict__ xT) {
    int tid = blockIdx.x * 256 + threadIdx.x;
    if (tid >= B_ * T_ * 4) return;
    int k = tid & 3;
    int r = tid >> 2;                                  // r = b*912 + t
    int b = r / T_;
    int t = r - b * T_;
    const float* p = x + ((size_t)r * 32 + k * 8);
    short8 v;
#pragma unroll
    for (int j = 0; j < 8; j++) v[j] = (short)bf16rne(p[j]);
    *(short8*)(xT + ((size_t)t * 512 + b) * 32 + k * 8) = v;
}

// ---------------------------------------------------------------------------
// Pipelined 4-layer LSTM scan. 64 blocks = 4 layers x 16 block-groups; each
// block time-interleaves TWO independent 16-sample groups (A,B) per step:
// one barrier serves two timestep computations, and the two groups' MFMA /
// trans / LDS phases mutually hide each other's latency (software occupancy
// doubling within the 2-wave/SIMD register budget: no wider fragments, no
// accx carry, frags die into MFMAs before the partner group's frags load).
__global__ __launch_bounds__(512, 2) void lstm_scan(
    const float* __restrict__ Wih0, const float* __restrict__ Whh0,
    const float* __restrict__ bih0, const float* __restrict__ bhh0,
    const float* __restrict__ Wih123, const float* __restrict__ Whh123,
    const float* __restrict__ bih123, const float* __restrict__ bhh123,
    char* __restrict__ ws) {
    const int tid  = threadIdx.x;
    const int wv   = tid >> 6;
    const int lane = tid & 63;
    const int col  = lane & 15;
    const int quad = lane >> 4;
    const int layer = blockIdx.x >> 4;
    const int g     = blockIdx.x & 15;
    const int b0    = g * 32;
    const bool lay0 = (layer == 0);

    unsigned* flags = (unsigned*)ws;                   // [4][16] chunks published
    unsigned* cons  = (unsigned*)(ws + 512);           // [4][16] chunks retired
    char* hN8 = ws + HN_OFF;
    const char* xTB = ws + XT_OFF;

    __shared__ unsigned short AhA[8][16][132];         // h ring, group A (slot=t&7)
    __shared__ unsigned short AhB[8][16][132];         // h ring, group B
    __shared__ unsigned short XlA[8][16][132];         // x stage, group A
    __shared__ unsigned short XlB[8][16][132];         // x stage, group B
    char* AhAB = (char*)AhA;
    char* AhBB = (char*)AhB;
    char* XlAB = (char*)XlA;
    char* XlBB = (char*)XlB;

    for (int i = tid; i < 8 * 16 * 132; i += 512) {
        ((unsigned short*)AhA)[i] = 0; ((unsigned short*)AhB)[i] = 0;
        ((unsigned short*)XlA)[i] = 0; ((unsigned short*)XlB)[i] = 0;
    }

    // ---- persistent weights, activation scale folded in ------------------
    short8 wh[4][4];
    short8 wx[4][4];
    float  bias_q[4];
    {
        const float *Wih, *Whh, *bih, *bhh;
        int kin, KX;
        if (layer == 0) { Wih = Wih0; Whh = Whh0; bih = bih0; bhh = bhh0; kin = 32; KX = 1; }
        else {
            Wih = Wih123 + (size_t)(layer - 1) * 512 * 128;
            Whh = Whh123 + (size_t)(layer - 1) * 512 * 128;
            bih = bih123 + (size_t)(layer - 1) * 512;
            bhh = bhh123 + (size_t)(layer - 1) * 512;
            kin = 128; KX = 4;
        }
#pragma unroll
        for (int q = 0; q < 4; q++) {
            const float sc = (q == 2) ? -2.88539008f : -1.44269504f;
            int row = q * 128 + wv * 16 + col;
            bias_q[q] = (bih[row] + bhh[row]) * sc;
#pragma unroll
            for (int kt = 0; kt < 4; kt++) {
                const float* ph = Whh + (size_t)row * 128 + kt * 32 + quad * 8;
                short8 v;
#pragma unroll
                for (int j = 0; j < 8; j++) v[j] = (short)bf16rne(ph[j] * sc);
                wh[q][kt] = v;
            }
#pragma unroll
            for (int kt = 0; kt < 4; kt++) {
                short8 v = {0, 0, 0, 0, 0, 0, 0, 0};
                if (kt < KX) {
                    const float* px = Wih + (size_t)row * kin + kt * 32 + quad * 8;
#pragma unroll
                    for (int j = 0; j < 8; j++) v[j] = (short)bf16rne(px[j] * sc);
                }
                wx[q][kt] = v;
            }
        }
    }

    unsigned* myflag   = &flags[layer * 16 + g];
    unsigned* prevflag = &flags[(layer > 0 ? layer - 1 : 0) * 16 + g];
    unsigned* mycons   = &cons[(layer > 0 ? layer - 1 : 0) * 16 + g];
    unsigned* nextcons = &cons[layer * 16 + g];
    char* prodA = ws + RING_OFF + (size_t)(layer * 32 + 2 * g) * RING_BPG;
    char* prodB = prodA + RING_BPG;
    char* consAp = ws + RING_OFF + (size_t)((layer > 0 ? layer - 1 : 0) * 32 + 2 * g) * RING_BPG;
    char* consBp = consAp + RING_BPG;

    // precomputed byte offsets
    const int ahrd  = col * 264 + quad * 16;                    // A-frag base
    const int hwr   = (quad * 4) * 264 + (wv * 16 + col) * 2;   // h write base
    const int exA   = (tid >> 5) * 264 + (tid & 31) * 8;        // export/stage LDS base
    const int rgo   = tid << 3;                                 // ring byte off (tid*8)
    const int xoffA = (b0 + col) * 64 + quad * 16;              // xT frag, group A
    // group B frag = xoffA + 1024

    ull xrA[2] = {0, 0}, xrB[2] = {0, 0};              // x prefetch ping-pong
    unsigned pf = 0, pc = 0;
    float c4A[4] = {0.f, 0.f, 0.f, 0.f};
    float c4B[4] = {0.f, 0.f, 0.f, 0.f};

    __syncthreads();                                   // LDS zeros visible

    // ---- prologue: stage x(0..5), preload x(6),x(7) ----------------------
    if (!lay0) {
        if (tid == 0) { while (ald(prevflag) < 2u) {} }
        __syncthreads();
#pragma unroll
        for (int s = 0; s < 6; s++) {
            ull a = ald8((const ull*)(consAp + s * 4096 + rgo));
            ull b = ald8((const ull*)(consBp + s * 4096 + rgo));
            *(ull*)(XlAB + s * 4224 + exA) = a;
            *(ull*)(XlBB + s * 4224 + exA) = b;
        }
        xrA[0] = ald8((const ull*)(consAp + 6 * 4096 + rgo));
        xrB[0] = ald8((const ull*)(consBp + 6 * 4096 + rgo));
        xrA[1] = ald8((const ull*)(consAp + 7 * 4096 + rgo));
        xrB[1] = ald8((const ull*)(consBp + 7 * 4096 + rgo));
        __syncthreads();
    }

    int c = 0;
    auto step = [&](auto UC) {
        constexpr int u   = UC.value;
        constexpr int eSl = (u + 7) & 7;               // slot of t-1 (export + h read)
        constexpr int xSl = u;                         // slot of x(t) / h(t) write
        constexpr int sSl = (u + 6) & 7;               // stage slot for x(t+6)
        constexpr int pp  = u & 1;
        const int t = c * 8 + u;

        if (u == 0 && tid == 0) {                      // snapshot flags once/chunk
            if (layer > 0 && c <= 111) pf = ald(prevflag);
            if (layer < 3 && c >= 8)   pc = ald(nextcons);
        }

        // ---- export h(t-1) -> rings (both groups, full-sector tid*8) ------
        if (layer < 3 && t > 0) {
            const int ch = ((u == 0) ? (c - 1) : c) & 7;
            ull hA = *(const ull*)(AhAB + eSl * 4224 + exA);
            ull hB = *(const ull*)(AhBB + eSl * 4224 + exA);
            ast8((ull*)(prodA + (size_t)ch * 32768 + eSl * 4096 + rgo), hA);
            ast8((ull*)(prodB + (size_t)ch * 32768 + eSl * 4096 + rgo), hB);
        }

        // ---- group A: frags + MFMAs --------------------------------------
        floatx4 accA[4];
#pragma unroll
        for (int q = 0; q < 4; q++) {
            floatx4 a = {bias_q[q], bias_q[q], bias_q[q], bias_q[q]};
            accA[q] = a;
        }
        {
            short8 ahA_[4];
            const char* ab = AhAB + eSl * 4224 + ahrd;
#pragma unroll
            for (int kt = 0; kt < 4; kt++) ahA_[kt] = *(const short8*)(ab + kt * 64);
            if (lay0) {
                short8 ax = *(const short8*)(xTB + (size_t)t * 32768 + xoffA);
#pragma unroll
                for (int q = 0; q < 4; q++)
                    accA[q] = __builtin_amdgcn_mfma_f32_16x16x32_bf16(ax, wx[q][0], accA[q], 0, 0, 0);
            } else {
                const char* xab = XlAB + xSl * 4224 + ahrd;
#pragma unroll
                for (int kt = 0; kt < 4; kt++) {
                    short8 ax = *(const short8*)(xab + kt * 64);
#pragma unroll
                    for (int q = 0; q < 4; q++)
                        accA[q] = __builtin_amdgcn_mfma_f32_16x16x32_bf16(ax, wx[q][kt], accA[q], 0, 0, 0);
                }
            }
#pragma unroll
            for (int kt = 0; kt < 4; kt++)
#pragma unroll
                for (int q = 0; q < 4; q++)
                    accA[q] = __builtin_amdgcn_mfma_f32_16x16x32_bf16(ahA_[kt], wh[q][kt], accA[q], 0, 0, 0);
        }

        // ---- group B: frags + MFMAs --------------------------------------
        floatx4 accB[4];
#pragma unroll
        for (int q = 0; q < 4; q++) {
            floatx4 a = {bias_q[q], bias_q[q], bias_q[q], bias_q[q]};
            accB[q] = a;
        }
        {
            short8 ahB_[4];
            const char* ab = AhBB + eSl * 4224 + ahrd;
#pragma unroll
            for (int kt = 0; kt < 4; kt++) ahB_[kt] = *(const short8*)(ab + kt * 64);
            if (lay0) {
                short8 ax = *(const short8*)(xTB + (size_t)t * 32768 + xoffA + 1024);
#pragma unroll
                for (int q = 0; q < 4; q++)
                    accB[q] = __builtin_amdgcn_mfma_f32_16x16x32_bf16(ax, wx[q][0], accB[q], 0, 0, 0);
            } else {
                const char* xab = XlBB + xSl * 4224 + ahrd;
#pragma unroll
                for (int kt = 0; kt < 4; kt++) {
                    short8 ax = *(const short8*)(xab + kt * 64);
#pragma unroll
                    for (int q = 0; q < 4; q++)
                        accB[q] = __builtin_amdgcn_mfma_f32_16x16x32_bf16(ax, wx[q][kt], accB[q], 0, 0, 0);
                }
            }
#pragma unroll
            for (int kt = 0; kt < 4; kt++)
#pragma unroll
                for (int q = 0; q < 4; q++)
                    accB[q] = __builtin_amdgcn_mfma_f32_16x16x32_bf16(ahB_[kt], wh[q][kt], accB[q], 0, 0, 0);
        }

        // ---- stage x(t+6) then import x(t+8) (fills MFMA-latency gap) -----
        if (!lay0) {
            if (t + 6 <= 911) {
                *(ull*)(XlAB + sSl * 4224 + exA) = xrA[pp];
                *(ull*)(XlBB + sSl * 4224 + exA) = xrB[pp];
            }
            if (t <= 903) {
                const int lch = (c + 1) & 7;
                xrA[pp] = ald8((const ull*)(consAp + (size_t)lch * 32768 + xSl * 4096 + rgo));
                xrB[pp] = ald8((const ull*)(consBp + (size_t)lch * 32768 + xSl * 4096 + rgo));
            }
        }

        // ---- gates A, h(t) -> AhA slot u ----------------------------------
        {
            char* hb = AhAB + xSl * 4224 + hwr;
#pragma unroll
            for (int r = 0; r < 4; r++) {
                float iv = fastsig(accA[0][r]);
                float fv = fastsig(accA[1][r]);
                float gr = fastsig(accA[2][r]);        // (tanh(g)+1)/2
                float ov = fastsig(accA[3][r]);
                float gt = 2.f * gr - 1.f;
                float cv = fv * c4A[r] + iv * gt;
                c4A[r] = cv;
                float rc = fastsig(-2.88539008f * cv);
                float hv = ov * (2.f * rc - 1.f);
                *(unsigned short*)(hb + r * 264) = bf16rne(hv);
            }
        }
        // ---- gates B, h(t) -> AhB slot u ----------------------------------
        {
            char* hb = AhBB + xSl * 4224 + hwr;
#pragma unroll
            for (int r = 0; r < 4; r++) {
                float iv = fastsig(accB[0][r]);
                float fv = fastsig(accB[1][r]);
                float gr = fastsig(accB[2][r]);
                float ov = fastsig(accB[3][r]);
                float gt = 2.f * gr - 1.f;
                float cv = fv * c4B[r] + iv * gt;
                c4B[r] = cv;
                float rc = fastsig(-2.88539008f * cv);
                float hv = ov * (2.f * rc - 1.f);
                *(unsigned short*)(hb + r * 264) = bf16rne(hv);
            }
        }

        // ---- sync cadence --------------------------------------------------
        if constexpr (u == 3) {
            __syncthreads();                           // full drain: release point
            if (tid == 0) {
                if (layer < 3 && c >= 1) ast32(myflag, (unsigned)c);
                if (layer > 0) ast32(mycons, (unsigned)c);
            }
        } else {
            if (u == 7 && tid == 0) {
                if (layer > 0 && c <= 111) {
                    unsigned tgt = c + 3;
                    if (pf < tgt) while (ald(prevflag) < tgt) {}
                }
                if (layer < 3 && c >= 8) {
                    unsigned tgt = c - 7;
                    if (pc < tgt) while (ald(nextcons) < tgt) {}
                }
            }
            bar_fast();
        }
    };

    for (c = 0; c < 114; ++c) {
        step(IC<0>{}); step(IC<1>{}); step(IC<2>{}); step(IC<3>{});
        step(IC<4>{}); step(IC<5>{}); step(IC<6>{}); step(IC<7>{});
    }

    // ---- epilogue: export h(911) (slot 7, chunk 113), publish, hN --------
    if (layer < 3) {
        ull hA = *(const ull*)(AhAB + 7 * 4224 + exA);
        ull hB = *(const ull*)(AhBB + 7 * 4224 + exA);
        ast8((ull*)(prodA + (size_t)(113 & 7) * 32768 + 7 * 4096 + rgo), hA);
        ast8((ull*)(prodB + (size_t)(113 & 7) * 32768 + 7 * 4096 + rgo), hB);
    }
    __syncthreads();                                   // drain ring stores
    if (tid == 0 && layer < 3) ast32(myflag, 114u);
    {
        ull hA = *(const ull*)(AhAB + 7 * 4224 + exA); // h[911]
        ull hB = *(const ull*)(AhBB + 7 * 4224 + exA);
        char* dA = hN8 + ((size_t)layer * 512 + b0 + (tid >> 5)) * 256 + (tid & 31) * 8;
        *(ull*)dA = hA;
        *(ull*)(dA + 16 * 256) = hB;
    }
}

// ---------------------------------------------------------------------------
// heads: hN [4][512][128] bf16 -> opt/tp/sl/lot, each [4][512][4] fp32
__global__ __launch_bounds__(256) void heads(
    const unsigned short* __restrict__ hN,
    const float* __restrict__ Wopt, const float* __restrict__ bopt,
    const float* __restrict__ Wlot, const float* __restrict__ blot,
    const float* __restrict__ Wtp,  const float* __restrict__ btp,
    const float* __restrict__ Wsl,  const float* __restrict__ bsl,
    float* __restrict__ out) {
    int tid = blockIdx.x * 256 + threadIdx.x;
    if (tid >= 4 * 4 * 512) return;
    int b  = tid & 511;
    int l  = (tid >> 9) & 3;
    int hd = tid >> 11;
    const float *W, *bb;
    if      (hd == 0) { W = Wopt; bb = bopt; }
    else if (hd == 1) { W = Wtp;  bb = btp;  }
    else if (hd == 2) { W = Wsl;  bb = bsl;  }
    else              { W = Wlot; bb = blot; }
    const unsigned short* h = hN + ((size_t)l * 512 + b) * 128;
    float z0 = bb[0], z1 = bb[1], z2 = bb[2], z3 = bb[3];
    for (int i = 0; i < 128; i++) {
        float hv = bf16tof(h[i]);
        z0 += hv * W[0 * 128 + i];
        z1 += hv * W[1 * 128 + i];
        z2 += hv * W[2 * 128 + i];
        z3 += hv * W[3 * 128 + i];
    }
    float o0, o1, o2, o3;
    if (hd == 0) {
        float m = fmaxf(fmaxf(z0, z1), fmaxf(z2, z3));
        float e0 = __builtin_amdgcn_exp2f((z0 - m) * 1.44269504f);
        float e1 = __builtin_amdgcn_exp2f((z1 - m) * 1.44269504f);
        float e2 = __builtin_amdgcn_exp2f((z2 - m) * 1.44269504f);
        float e3 = __builtin_amdgcn_exp2f((z3 - m) * 1.44269504f);
        float rs = __builtin_amdgcn_rcpf(e0 + e1 + e2 + e3);
        float p0 = e0 * rs, p1 = e1 * rs, p2 = e2 * rs, p3 = e3 * rs;
        float m2 = fmaxf(fmaxf(p0, p1), fmaxf(p2, p3));
        float f0 = __builtin_amdgcn_exp2f((p0 - m2) * 1.44269504f);
        float f1 = __builtin_amdgcn_exp2f((p1 - m2) * 1.44269504f);
        float f2 = __builtin_amdgcn_exp2f((p2 - m2) * 1.44269504f);
        float f3 = __builtin_amdgcn_exp2f((p3 - m2) * 1.44269504f);
        float rs2 = __builtin_amdgcn_rcpf(f0 + f1 + f2 + f3);
        o0 = f0 * rs2; o1 = f1 * rs2; o2 = f2 * rs2; o3 = f3 * rs2;
    } else {
        o0 = sigm(sigm(z0)); o1 = sigm(sigm(z1));
        o2 = sigm(sigm(z2)); o3 = sigm(sigm(z3));
    }
    float* o = out + (size_t)hd * 8192 + ((size_t)l * 512 + b) * 4;
    o[0] = o0; o[1] = o1; o[2] = o2; o[3] = o3;
}

// ---------------------------------------------------------------------------
extern "C" void kernel_launch(void* const* d_in, const int* in_sizes, int n_in,
                              void* d_out, int out_size, void* d_ws, size_t ws_size,
                              hipStream_t stream) {
    (void)in_sizes; (void)n_in; (void)out_size; (void)ws_size;
    const float* x      = (const float*)d_in[0];
    const float* Wih0   = (const float*)d_in[1];
    const float* Whh0   = (const float*)d_in[2];
    const float* bih0   = (const float*)d_in[3];
    const float* bhh0   = (const float*)d_in[4];
    const float* Wih123 = (const float*)d_in[5];
    const float* Whh123 = (const float*)d_in[6];
    const float* bih123 = (const float*)d_in[7];
    const float* bhh123 = (const float*)d_in[8];
    const float* Wopt = (const float*)d_in[9];
    const float* bopt = (const float*)d_in[10];
    const float* Wlot = (const float*)d_in[11];
    const float* blot = (const float*)d_in[12];
    const float* Wtp  = (const float*)d_in[13];
    const float* btp  = (const float*)d_in[14];
    const float* Wsl  = (const float*)d_in[15];
    const float* bsl  = (const float*)d_in[16];
    char* ws = (char*)d_ws;

    hipMemsetAsync(ws, 0, 1024, stream);               // flags + cons
    xpose<<<(B_ * T_ * 4 + 255) / 256, 256, 0, stream>>>(x, (unsigned short*)(ws + XT_OFF));
    lstm_scan<<<64, 512, 0, stream>>>(Wih0, Whh0, bih0, bhh0,
                                      Wih123, Whh123, bih123, bhh123, ws);
    heads<<<32, 256, 0, stream>>>((const unsigned short*)(ws + HN_OFF),
                                  Wopt, bopt, Wlot, blot, Wtp, btp, Wsl, bsl,
                                  (float*)d_out);
}

// Round 4
// 2154.750 us; speedup vs baseline: 2.5320x; 2.1142x over previous
//
#include <hip/hip_runtime.h>

#define DEV __device__ __forceinline__

typedef __attribute__((ext_vector_type(8))) short short8;
typedef __attribute__((ext_vector_type(4))) float floatx4;
typedef unsigned long long ull;

static constexpr int B_ = 512, T_ = 912, H_ = 128, F_ = 32;
static constexpr size_t HN_OFF   = 1024;                       // bf16 hN[4][512][128]
static constexpr size_t XT_OFF   = HN_OFF + (size_t)4 * 512 * 128 * 2;   // 525312
static constexpr size_t RING_OFF = XT_OFF + (size_t)T_ * B_ * F_ * 2;    // 30409728
// ring per boundary-group: 8 regions x 32KB ([slot][16 rows][256B])
static constexpr size_t RING_BPG = 8 * 32768;                  // 256 KB

template <int N> struct IC { static constexpr int value = N; };

DEV unsigned short bf16rne(float f) {
    unsigned u = __builtin_bit_cast(unsigned, f);
    u += 0x7FFFu + ((u >> 16) & 1u);
    return (unsigned short)(u >> 16);
}
DEV float bf16tof(unsigned short u) {
    return __builtin_bit_cast(float, ((unsigned)u) << 16);
}
DEV float fastsig(float y) {     // rcp(1+exp2(y))
    return __builtin_amdgcn_rcpf(1.f + __builtin_amdgcn_exp2f(y));
}
DEV float sigm(float x) { return fastsig(-1.44269504f * x); }
DEV unsigned ald(const unsigned* p) {
    return __hip_atomic_load(p, __ATOMIC_RELAXED, __HIP_MEMORY_SCOPE_AGENT);
}
DEV void ast32(unsigned* p, unsigned v) {
    __hip_atomic_store(p, v, __ATOMIC_RELAXED, __HIP_MEMORY_SCOPE_AGENT);
}
DEV ull ald8(const ull* p) {
    return __hip_atomic_load(p, __ATOMIC_RELAXED, __HIP_MEMORY_SCOPE_AGENT);
}
DEV void ast8(ull* p, ull v) {
    __hip_atomic_store(p, v, __ATOMIC_RELAXED, __HIP_MEMORY_SCOPE_AGENT);
}
DEV void bar_fast() {            // LDS-only barrier: no vmcnt drain
    asm volatile("s_waitcnt lgkmcnt(0)\n\ts_barrier" ::: "memory");
}

// ---------------------------------------------------------------------------
// x [B][T][32] fp32  ->  xT [T][B][32] bf16
__global__ __launch_bounds__(256) void xpose(const float* __restrict__ x,
                                             unsigned short* __restrict__ xT) {
    int tid = blockIdx.x * 256 + threadIdx.x;
    if (tid >= B_ * T_ * 4) return;
    int k = tid & 3;
    int r = tid >> 2;                                  // r = b*912 + t
    int b = r / T_;
    int t = r - b * T_;
    const float* p = x + ((size_t)r * 32 + k * 8);
    short8 v;
#pragma unroll
    for (int j = 0; j < 8; j++) v[j] = (short)bf16rne(p[j]);
    *(short8*)(xT + ((size_t)t * 512 + b) * 32 + k * 8) = v;
}

// ---------------------------------------------------------------------------
// Pipelined 4-layer LSTM scan. 128 blocks = 4 layers x 32 groups (16 samples).
// Round-0 structure with three scheduling changes (bit-exact math):
//  1) rec MFMAs q-outer with per-q IN-PLACE sigmoids: gate trans ops issue
//     into the matrix-pipe shadow of the remaining q chains.
//  2) axn (x(t+1)) LDS frag reads deferred to mid-rec: halves the
//     post-barrier DS storm and starts rec MFMAs earlier.
//  3) ring export distributed: 1 b64 LDS read + 1 ast8 per thread per step
//     instead of a 16-op burst at chunk boundaries.
__global__ __launch_bounds__(512, 2) void lstm_scan(
    const float* __restrict__ Wih0, const float* __restrict__ Whh0,
    const float* __restrict__ bih0, const float* __restrict__ bhh0,
    const float* __restrict__ Wih123, const float* __restrict__ Whh123,
    const float* __restrict__ bih123, const float* __restrict__ bhh123,
    char* __restrict__ ws) {
    const int tid  = threadIdx.x;
    const int wv   = tid >> 6;
    const int lane = tid & 63;
    const int col  = lane & 15;
    const int quad = lane >> 4;
    const int layer = blockIdx.x >> 5;
    const int grp   = blockIdx.x & 31;
    const int b0    = grp * 16;

    unsigned* flags = (unsigned*)ws;                   // [4][32] chunks published
    unsigned* cons  = (unsigned*)(ws + 512);           // [4][32] chunks loaded
    char* hN8 = ws + HN_OFF;
    const char* xTB = ws + XT_OFF;

    __shared__ unsigned short Ah[16][16][132];         // h history ring (slot = t&15)
    __shared__ unsigned short Xl[16][16][132];         // staged input (slot = t&15)
    char* AhB = (char*)Ah;
    char* XlB = (char*)Xl;

    for (int i = tid; i < 16 * 16 * 132; i += 512) {
        ((unsigned short*)Ah)[i] = 0;
        ((unsigned short*)Xl)[i] = 0;
    }

    // ---- persistent weights, activation scale folded in ------------------
    short8 wh[4][4];
    short8 wx[4][4];
    float  bias_q[4];
    {
        const float *Wih, *Whh, *bih, *bhh;
        int kin, KX;
        if (layer == 0) { Wih = Wih0; Whh = Whh0; bih = bih0; bhh = bhh0; kin = 32; KX = 1; }
        else {
            Wih = Wih123 + (size_t)(layer - 1) * 512 * 128;
            Whh = Whh123 + (size_t)(layer - 1) * 512 * 128;
            bih = bih123 + (size_t)(layer - 1) * 512;
            bhh = bhh123 + (size_t)(layer - 1) * 512;
            kin = 128; KX = 4;
        }
#pragma unroll
        for (int q = 0; q < 4; q++) {
            const float sc = (q == 2) ? -2.88539008f : -1.44269504f;
            int row = q * 128 + wv * 16 + col;
            bias_q[q] = (bih[row] + bhh[row]) * sc;
#pragma unroll
            for (int kt = 0; kt < 4; kt++) {
                const float* ph = Whh + (size_t)row * 128 + kt * 32 + quad * 8;
                short8 v;
#pragma unroll
                for (int j = 0; j < 8; j++) v[j] = (short)bf16rne(ph[j] * sc);
                wh[q][kt] = v;
            }
#pragma unroll
            for (int kt = 0; kt < 4; kt++) {
                short8 v = {0, 0, 0, 0, 0, 0, 0, 0};
                if (kt < KX) {
                    const float* px = Wih + (size_t)row * kin + kt * 32 + quad * 8;
#pragma unroll
                    for (int j = 0; j < 8; j++) v[j] = (short)bf16rne(px[j] * sc);
                }
                wx[q][kt] = v;
            }
        }
    }

    unsigned* myflag   = &flags[layer * 32 + grp];
    unsigned* prevflag = &flags[(layer > 0 ? layer - 1 : 0) * 32 + grp];
    unsigned* mycons   = &cons[(layer > 0 ? layer - 1 : 0) * 32 + grp];
    unsigned* nextcons = &cons[layer * 32 + grp];
    char* prodRing = ws + RING_OFF + (size_t)(layer * 32 + grp) * RING_BPG;
    char* consRing = ws + RING_OFF + (size_t)((layer > 0 ? layer - 1 : 0) * 32 + grp) * RING_BPG;

    // precomputed byte offsets (constants through the whole kernel)
    const int ahrd  = col * 264 + quad * 16;                    // A-frag base
    const int hwr   = (quad * 4) * 264 + (wv * 16 + col) * 2;   // h write base
    const int exOff = (tid >> 5) * 264 + (tid & 31) * 8;        // export/stage base
    const int consOff = (tid >> 5) * 256 + (tid & 31) * 8;      // ring qword offset
    const int xgOff = (tid >> 6) * 32768 + b0 * 64 + (tid & 63) * 16;   // xT chunk
    const int xlw0  = (tid >> 6) * 4224 + ((tid >> 2) & 15) * 264 + (tid & 3) * 16;

    ull    xin[8];
    short8 xv = {0, 0, 0, 0, 0, 0, 0, 0};
    unsigned pf = 0, pc = 0;
    float c4[4] = {0.f, 0.f, 0.f, 0.f};
    floatx4 accx[4];               // carried x-part partial sums for step t+1

    __syncthreads();                                   // LDS zeros visible

    // ---- prologue: load+stage chunks 0,1 ---------------------------------
    if (layer > 0) {
        if (tid == 0) { while (ald(prevflag) < 2u) {} }
        __syncthreads();
#pragma unroll
        for (int j = 0; j < 16; j++) {
            ull d = ald8((const ull*)(consRing + (size_t)j * 4096 + consOff));
            *(ull*)(XlB + exOff + j * 4224) = d;
        }
    } else {
#pragma unroll
        for (int c0 = 0; c0 < 2; c0++) {
            short8 v = *(const short8*)(xTB + (size_t)c0 * 262144 + xgOff);
            *(short8*)(XlB + xlw0 + c0 * 33792) = v;
        }
    }
    __syncthreads();

    // ---- prologue: accx for t=0 (x-part from Xl slot 0) ------------------
    {
        short8 ax0[4];
#pragma unroll
        for (int kt = 0; kt < 4; kt++)
            ax0[kt] = *(const short8*)(XlB + ahrd + 0 * 4224 + kt * 64);
#pragma unroll
        for (int q = 0; q < 4; q++) {
            floatx4 a = {bias_q[q], bias_q[q], bias_q[q], bias_q[q]};
            accx[q] = a;
        }
#pragma unroll
        for (int kt = 0; kt < 4; kt++)
#pragma unroll
            for (int q = 0; q < 4; q++)
                accx[q] = __builtin_amdgcn_mfma_f32_16x16x32_bf16(ax0[kt], wx[q][kt], accx[q], 0, 0, 0);
    }

    int c = 0;
    auto step = [&](auto UC) {
        constexpr int u   = UC.value;
        constexpr bool bnd = (u == 0 || u == 8);
        constexpr bool stg = (u == 3 || u == 11);
        constexpr bool ver = (u == 7 || u == 15);
        constexpr int sph = (u < 8) ? 8 : 0;           // slot base for export/stage
        const int cc = c + (u >> 3);
        const int t  = cc * 8 + (u & 7);               // global timestep

        if (bnd) {
            if (tid == 0) {
                if (layer > 0 && cc <= 111) pf = ald(prevflag);
                if (layer < 3 && cc >= 8)   pc = ald(nextcons);
            }
            if (layer > 0 && cc <= 112) {              // load chunk cc+1
                const char* rb2 = consRing + (size_t)((cc + 1) & 7) * 32768 + consOff;
#pragma unroll
                for (int j = 0; j < 8; j++)
                    xin[j] = ald8((const ull*)(rb2 + j * 4096));
            }
            if (layer == 0 && cc <= 112)
                xv = *(const short8*)(xTB + (size_t)(cc + 1) * 262144 + xgOff);
        }

        // ---- distributed export: h(t-1) -> ring (1 b64 + 1 ast8/thread) ---
        if (layer < 3 && t > 0) {
            const int te = t - 1;
            ull hv = *(const ull*)(AhB + exOff + ((u + 15) & 15) * 4224);
            ast8((ull*)(prodRing + (size_t)((te >> 3) & 7) * 32768
                        + (te & 7) * 4096 + tid * 8), hv);
        }

        if (stg) {                                     // stage chunk cc+1 into Xl
            if (layer > 0) {
#pragma unroll
                for (int j = 0; j < 8; j++)
                    *(ull*)(XlB + exOff + (sph + j) * 4224) = xin[j];
            } else {
                *(short8*)(XlB + xlw0 + sph * 4224) = xv;
            }
        }

        // ---- A fragments: h(t-1) only (axn deferred to mid-rec) -----------
        short8 ah[4], axn[4];
#pragma unroll
        for (int kt = 0; kt < 4; kt++)
            ah[kt] = *(const short8*)(AhB + ahrd + ((u + 15) & 15) * 4224 + kt * 64);

        // ---- rec MFMAs q-outer; per-q IN-PLACE sigmoid into MFMA shadow ---
        floatx4 acc[4];
#pragma unroll
        for (int q = 0; q < 4; q++) {
            floatx4 a = accx[q];
#pragma unroll
            for (int kt = 0; kt < 4; kt++)
                a = __builtin_amdgcn_mfma_f32_16x16x32_bf16(ah[kt], wh[q][kt], a, 0, 0, 0);
#pragma unroll
            for (int r = 0; r < 4; r++) a[r] = fastsig(a[r]);
            acc[q] = a;
            if (q == 1) {                              // mid-rec: pull x(t+1) frags
#pragma unroll
                for (int kt = 0; kt < 4; kt++)
                    axn[kt] = *(const short8*)(XlB + ahrd + ((u + 1) & 15) * 4224 + kt * 64);
            }
        }

        // ---- c/h updates INTERLEAVED with x-MFMAs for t+1 ------------------
#pragma unroll
        for (int q = 0; q < 4; q++) {
            floatx4 a = {bias_q[q], bias_q[q], bias_q[q], bias_q[q]};
            accx[q] = a;
        }
#pragma unroll
        for (int r = 0; r < 4; r++) {
            float iv = acc[0][r];
            float fv = acc[1][r];
            float gr = acc[2][r];                      // (tanh(g)+1)/2
            float ov = acc[3][r];
            // independent x-MFMA group (kt = r) fills the trans-latency window
#pragma unroll
            for (int q = 0; q < 4; q++)
                accx[q] = __builtin_amdgcn_mfma_f32_16x16x32_bf16(axn[r], wx[q][r], accx[q], 0, 0, 0);
            float gt = 2.f * gr - 1.f;
            float cv = fv * c4[r] + iv * gt;
            c4[r] = cv;
            float rc = fastsig(-2.88539008f * cv);
            float hv = ov * (2.f * rc - 1.f);
            *(unsigned short*)(AhB + hwr + u * 4224 + r * 264) = bf16rne(hv);
        }

        if (stg) {
            __syncthreads();                           // full drain: release point
            if (tid == 0) {
                if (layer < 3 && cc >= 1) ast32(myflag, (unsigned)cc);
                if (layer > 0) ast32(mycons, (unsigned)(cc + 2));
            }
        } else {
            if (ver && tid == 0) {
                if (layer > 0 && cc <= 111) {
                    unsigned tgt = cc + 3;
                    if (pf < tgt) while (ald(prevflag) < tgt) {}
                }
                if (layer < 3 && cc >= 8) {
                    unsigned tgt = cc - 7;
                    if (pc < tgt) while (ald(nextcons) < tgt) {}
                }
            }
            bar_fast();
        }
    };

    for (c = 0; c < 114; c += 2) {
        step(IC<0>{});  step(IC<1>{});  step(IC<2>{});  step(IC<3>{});
        step(IC<4>{});  step(IC<5>{});  step(IC<6>{});  step(IC<7>{});
        step(IC<8>{});  step(IC<9>{});  step(IC<10>{}); step(IC<11>{});
        step(IC<12>{}); step(IC<13>{}); step(IC<14>{}); step(IC<15>{});
    }

    // ---- epilogue: export h(911), publish, export hN ---------------------
    if (layer < 3) {
        ull hv = *(const ull*)(AhB + exOff + 15 * 4224);
        ast8((ull*)(prodRing + (size_t)(113 & 7) * 32768 + 7 * 4096 + tid * 8), hv);
    }
    __syncthreads();                                   // drain ring stores
    if (tid == 0 && layer < 3) ast32(myflag, 114u);
    {
        ull hv = *(const ull*)(AhB + exOff + 15 * 4224);   // h[911]
        *(ull*)(hN8 + ((size_t)layer * 512 + b0 + (tid >> 5)) * 256 + (tid & 31) * 8) = hv;
    }
}

// ---------------------------------------------------------------------------
// heads: hN [4][512][128] bf16 -> opt/tp/sl/lot, each [4][512][4] fp32
__global__ __launch_bounds__(256) void heads(
    const unsigned short* __restrict__ hN,
    const float* __restrict__ Wopt, const float* __restrict__ bopt,
    const float* __restrict__ Wlot, const float* __restrict__ blot,
    const float* __restrict__ Wtp,  const float* __restrict__ btp,
    const float* __restrict__ Wsl,  const float* __restrict__ bsl,
    float* __restrict__ out) {
    int tid = blockIdx.x * 256 + threadIdx.x;
    if (tid >= 4 * 4 * 512) return;
    int b  = tid & 511;
    int l  = (tid >> 9) & 3;
    int hd = tid >> 11;
    const float *W, *bb;
    if      (hd == 0) { W = Wopt; bb = bopt; }
    else if (hd == 1) { W = Wtp;  bb = btp;  }
    else if (hd == 2) { W = Wsl;  bb = bsl;  }
    else              { W = Wlot; bb = blot; }
    const unsigned short* h = hN + ((size_t)l * 512 + b) * 128;
    float z0 = bb[0], z1 = bb[1], z2 = bb[2], z3 = bb[3];
    for (int i = 0; i < 128; i++) {
        float hv = bf16tof(h[i]);
        z0 += hv * W[0 * 128 + i];
        z1 += hv * W[1 * 128 + i];
        z2 += hv * W[2 * 128 + i];
        z3 += hv * W[3 * 128 + i];
    }
    float o0, o1, o2, o3;
    if (hd == 0) {
        float m = fmaxf(fmaxf(z0, z1), fmaxf(z2, z3));
        float e0 = __builtin_amdgcn_exp2f((z0 - m) * 1.44269504f);
        float e1 = __builtin_amdgcn_exp2f((z1 - m) * 1.44269504f);
        float e2 = __builtin_amdgcn_exp2f((z2 - m) * 1.44269504f);
        float e3 = __builtin_amdgcn_exp2f((z3 - m) * 1.44269504f);
        float rs = __builtin_amdgcn_rcpf(e0 + e1 + e2 + e3);
        float p0 = e0 * rs, p1 = e1 * rs, p2 = e2 * rs, p3 = e3 * rs;
        float m2 = fmaxf(fmaxf(p0, p1), fmaxf(p2, p3));
        float f0 = __builtin_amdgcn_exp2f((p0 - m2) * 1.44269504f);
        float f1 = __builtin_amdgcn_exp2f((p1 - m2) * 1.44269504f);
        float f2 = __builtin_amdgcn_exp2f((p2 - m2) * 1.44269504f);
        float f3 = __builtin_amdgcn_exp2f((p3 - m2) * 1.44269504f);
        float rs2 = __builtin_amdgcn_rcpf(f0 + f1 + f2 + f3);
        o0 = f0 * rs2; o1 = f1 * rs2; o2 = f2 * rs2; o3 = f3 * rs2;
    } else {
        o0 = sigm(sigm(z0)); o1 = sigm(sigm(z1));
        o2 = sigm(sigm(z2)); o3 = sigm(sigm(z3));
    }
    float* o = out + (size_t)hd * 8192 + ((size_t)l * 512 + b) * 4;
    o[0] = o0; o[1] = o1; o[2] = o2; o[3] = o3;
}

// ---------------------------------------------------------------------------
extern "C" void kernel_launch(void* const* d_in, const int* in_sizes, int n_in,
                              void* d_out, int out_size, void* d_ws, size_t ws_size,
                              hipStream_t stream) {
    (void)in_sizes; (void)n_in; (void)out_size; (void)ws_size;
    const float* x      = (const float*)d_in[0];
    const float* Wih0   = (const float*)d_in[1];
    const float* Whh0   = (const float*)d_in[2];
    const float* bih0   = (const float*)d_in[3];
    const float* bhh0   = (const float*)d_in[4];
    const float* Wih123 = (const float*)d_in[5];
    const float* Whh123 = (const float*)d_in[6];
    const float* bih123 = (const float*)d_in[7];
    const float* bhh123 = (const float*)d_in[8];
    const float* Wopt = (const float*)d_in[9];
    const float* bopt = (const float*)d_in[10];
    const float* Wlot = (const float*)d_in[11];
    const float* blot = (const float*)d_in[12];
    const float* Wtp  = (const float*)d_in[13];
    const float* btp  = (const float*)d_in[14];
    const float* Wsl  = (const float*)d_in[15];
    const float* bsl  = (const float*)d_in[16];
    char* ws = (char*)d_ws;

    hipMemsetAsync(ws, 0, 1024, stream);               // flags + cons
    xpose<<<(B_ * T_ * 4 + 255) / 256, 256, 0, stream>>>(x, (unsigned short*)(ws + XT_OFF));
    lstm_scan<<<128, 512, 0, stream>>>(Wih0, Whh0, bih0, bhh0,
                                       Wih123, Whh123, bih123, bhh123, ws);
    heads<<<32, 256, 0, stream>>>((const unsigned short*)(ws + HN_OFF),
                                  Wopt, bopt, Wlot, blot, Wtp, btp, Wsl, bsl,
                                  (float*)d_out);
}